// Round 1
// 3064.124 us; speedup vs baseline: 3.2036x; 3.2036x over previous
//
#include <hip/hip_runtime.h>

// Problem constants (B=128, T=256, H=1024, V=4096)
#define T_STEPS 256
#define BATCH   128
#define HDIM    1024
#define VDIM    4096
#define BH      (BATCH * HDIM)

typedef _Float16 half8 __attribute__((ext_vector_type(8)));
typedef _Float16 half4 __attribute__((ext_vector_type(4)));
typedef float    floatx4 __attribute__((ext_vector_type(4)));

__device__ __forceinline__ half8 ld_h8(const _Float16* p) { return *(const half8*)p; }

__device__ __forceinline__ void async16(void* l, const void* g) {
  // global->LDS DMA, 16B per lane; LDS dest = wave-uniform base + lane*16
  __builtin_amdgcn_global_load_lds(
      (const __attribute__((address_space(1))) unsigned int*)g,
      (__attribute__((address_space(3))) unsigned int*)l, 16, 0, 0);
}

// ---------------- per-group flag sync (monotonic counters, no reset/ABA) ----
__device__ __forceinline__ void wait_ge(unsigned* f, unsigned tgt) {
  while (__hip_atomic_load(f, __ATOMIC_RELAXED, __HIP_MEMORY_SCOPE_AGENT) < tgt)
    __builtin_amdgcn_s_sleep(2);
  // one acquire to invalidate caches after the spin (orders subsequent reads)
  (void)__hip_atomic_load(f, __ATOMIC_ACQUIRE, __HIP_MEMORY_SCOPE_AGENT);
}
__device__ __forceinline__ void signal_inc(unsigned* f) {
  __hip_atomic_fetch_add(f, 1u, __ATOMIC_RELEASE, __HIP_MEMORY_SCOPE_AGENT);
}

// Swizzled LDS fragment read: tile = 16 rows x 128 chunks(16B); LDS chunk
// (row, s) holds global chunk (row, s ^ (row&7)) -> read chunk w at s = w^(row&7).
__device__ __forceinline__ half8 lds_frag(const char* base, int row, int w) {
  return *(const half8*)(base + row * 2048 + ((w ^ (row & 7)) << 4));
}

// ---------------- fp32 -> fp16 weight conversion ----------------
__global__ __launch_bounds__(256) void f32_to_f16_kernel(
    const float* __restrict__ in, _Float16* __restrict__ out, int n4) {
  int i = blockIdx.x * 256 + threadIdx.x;
  if (i < n4) {
    float4 v = ((const float4*)in)[i];
    half4 h;
    h[0] = (_Float16)v.x; h[1] = (_Float16)v.y;
    h[2] = (_Float16)v.z; h[3] = (_Float16)v.w;
    ((half4*)out)[i] = h;
  }
}

// ---------------- persistent recurrent kernel ----------------
// Grid: 256 wgs x 256 thr (1/CU). wgs [0,128): layer0, [128,256): layer1.
// Uniform tile: 16 batch rows x 64 cols per wg (8 rowgroups x 16 colgroups).
// Weights VGPR-resident per lane (its output column's full K). A-tiles (h
// state) staged to LDS per step via global_load_lds with XOR(row&7) swizzle.
// Sync: per-rowgroup monotonic counters cnt0/cnt1 (16 producers each).
__global__ __launch_bounds__(256, 1) void rnn_kernel(
    const float* __restrict__ x,      // [B, T]
    const float* __restrict__ Wih0,   // [H]
    const float* __restrict__ bih0, const float* __restrict__ bhh0,
    const float* __restrict__ bih1, const float* __restrict__ bhh1,
    const _Float16* __restrict__ W0h, // [H][H] fp16
    const _Float16* __restrict__ W1i, // [H][H]
    const _Float16* __restrict__ W1h, // [H][H]
    _Float16* __restrict__ h0buf,     // [2][B][H] fp16 (slot 1 zeroed)
    _Float16* __restrict__ h1h,       // [T+1][B][H] fp16 (slot 0 zeroed)
    float* __restrict__ outh,         // d_out + B*T*V : [2][B][H] fp32
    unsigned* __restrict__ cnt0,      // [8][256] counters, 16B stride
    unsigned* __restrict__ cnt1) {    // [8][256]
  __shared__ __align__(16) char smem[65536];
  const int tid  = threadIdx.x;
  const int wv   = tid >> 6;
  const int lane = tid & 63;
  const int l15  = lane & 15;
  const int q    = lane >> 4;

  const int bid   = blockIdx.x;
  const int layer = bid >> 7;
  const int sub   = bid & 127;
  const int rg    = sub & 7;        // rowgroup: batch rows [rg*16, +16)
  const int cg    = sub >> 3;       // colgroup: cols [cg*64, +64)
  const int rowbase = rg * 16;
  const int j     = cg * 64 + wv * 16 + l15;  // output column this lane owns
  const int qe    = q * 8;          // k-offset within a 32-wide MFMA step

  if (layer == 0) {
    // ---- resident W_hh0 fragments: column j, all K (32 x half8 = 128 VGPR)
    half8 w0r[32];
#pragma unroll
    for (int m = 0; m < 32; ++m)
      w0r[m] = ld_h8(W0h + (size_t)j * HDIM + m * 32 + qe);
    const float wih = Wih0[j];
    const float bb  = bih0[j] + bhh0[j];
    // ---- x table for our 16 rows -> LDS [16][256] f32 at smem+32768
    float* lx = (float*)(smem + 32768);
#pragma unroll
    for (int it = 0; it < 16; ++it)
      lx[it * 256 + tid] = x[rowbase * T_STEPS + it * 256 + tid];
    __syncthreads();

    for (int p = 0; p < T_STEPS; ++p) {
      if (tid == 0) {
        if (p >= 1) wait_ge(cnt0 + (((rg << 8) | (p - 1)) << 2), 16u);  // own group done p-1
        if (p >= 2) wait_ge(cnt1 + (((rg << 8) | (p - 2)) << 2), 16u);  // L1 consumed slot
      }
      __syncthreads();  // also guards LDS A-tile reuse across steps

      // stage A = h0(p-1)[rows rg] (32 KB) into LDS, pre-swizzled source
      const _Float16* Ag = h0buf + (size_t)((p + 1) & 1) * BH + rowbase * HDIM;
#pragma unroll
      for (int it = 0; it < 8; ++it) {
        int c = it * 256 + tid;            // chunk 0..2047
        int row = c >> 7, cr = c & 127;
        async16(smem + it * 4096 + wv * 1024,
                Ag + row * HDIM + ((cr ^ (row & 7)) << 3));
      }
      asm volatile("s_waitcnt vmcnt(0)" ::: "memory");
      __syncthreads();

      floatx4 acc0 = {0.f, 0.f, 0.f, 0.f}, acc1 = {0.f, 0.f, 0.f, 0.f};
#pragma unroll
      for (int t = 0; t < 16; ++t) {
        acc0 = __builtin_amdgcn_mfma_f32_16x16x32_f16(
            lds_frag(smem, l15, 4 * t + q), w0r[t], acc0, 0, 0, 0);
        acc1 = __builtin_amdgcn_mfma_f32_16x16x32_f16(
            lds_frag(smem, l15, 64 + 4 * t + q), w0r[16 + t], acc1, 0, 0, 0);
      }
      floatx4 z = acc0 + acc1;
      _Float16* D = h0buf + (size_t)(p & 1) * BH;
#pragma unroll
      for (int r = 0; r < 4; ++r) {
        int b = rowbase + q * 4 + r;       // D row = q*4+reg
        float h = tanhf(z[r] + lx[(q * 4 + r) * 256 + p] * wih + bb);
        D[b * HDIM + j] = (_Float16)h;
        if (p == T_STEPS - 1) outh[b * HDIM + j] = h;
      }
      asm volatile("s_waitcnt vmcnt(0)" ::: "memory");
      __syncthreads();
      if (tid == 0) signal_inc(cnt0 + (((rg << 8) | p) << 2));
    }
  } else {
    // ---- resident W_ih1 + W_hh1 fragments (64 x half8 = 256 VGPR)
    half8 w1r[32], w2r[32];
#pragma unroll
    for (int m = 0; m < 32; ++m) {
      w1r[m] = ld_h8(W1i + (size_t)j * HDIM + m * 32 + qe);
      w2r[m] = ld_h8(W1h + (size_t)j * HDIM + m * 32 + qe);
    }
    const float bb = bih1[j] + bhh1[j];

    for (int i = 0; i < T_STEPS; ++i) {
      if (tid == 0) {
        wait_ge(cnt0 + (((rg << 8) | i) << 2), 16u);                    // h0(i) ready
        if (i >= 1) wait_ge(cnt1 + (((rg << 8) | (i - 1)) << 2), 16u);  // h1(i-1) ready
      }
      __syncthreads();

      // stage A1 = h0(i)[rows rg], A2 = h1(i-1)[rows rg] (32 KB each)
      const _Float16* A1 = h0buf + (size_t)(i & 1) * BH + rowbase * HDIM;
      const _Float16* A2 = h1h + (size_t)i * BH + rowbase * HDIM;
#pragma unroll
      for (int it = 0; it < 8; ++it) {
        int c = it * 256 + tid;
        int row = c >> 7, cr = c & 127;
        int so = row * HDIM + ((cr ^ (row & 7)) << 3);
        async16(smem + it * 4096 + wv * 1024, A1 + so);
        async16(smem + 32768 + it * 4096 + wv * 1024, A2 + so);
      }
      asm volatile("s_waitcnt vmcnt(0)" ::: "memory");
      __syncthreads();

      floatx4 a00 = {0.f,0.f,0.f,0.f}, a01 = {0.f,0.f,0.f,0.f};
      floatx4 a10 = {0.f,0.f,0.f,0.f}, a11 = {0.f,0.f,0.f,0.f};
#pragma unroll
      for (int t = 0; t < 16; ++t) {
        a00 = __builtin_amdgcn_mfma_f32_16x16x32_f16(
            lds_frag(smem, l15, 4 * t + q),              w1r[t],      a00, 0, 0, 0);
        a01 = __builtin_amdgcn_mfma_f32_16x16x32_f16(
            lds_frag(smem, l15, 64 + 4 * t + q),         w1r[16 + t], a01, 0, 0, 0);
        a10 = __builtin_amdgcn_mfma_f32_16x16x32_f16(
            lds_frag(smem + 32768, l15, 4 * t + q),      w2r[t],      a10, 0, 0, 0);
        a11 = __builtin_amdgcn_mfma_f32_16x16x32_f16(
            lds_frag(smem + 32768, l15, 64 + 4 * t + q), w2r[16 + t], a11, 0, 0, 0);
      }
      floatx4 z = (a00 + a01) + (a10 + a11);
      _Float16* D = h1h + (size_t)(i + 1) * BH;
#pragma unroll
      for (int r = 0; r < 4; ++r) {
        int b = rowbase + q * 4 + r;
        float h = tanhf(z[r] + bb);
        D[b * HDIM + j] = (_Float16)h;
        if (i == T_STEPS - 1) outh[BH + b * HDIM + j] = h;
      }
      asm volatile("s_waitcnt vmcnt(0)" ::: "memory");
      __syncthreads();
      if (tid == 0) signal_inc(cnt1 + (((rg << 8) | i) << 2));
    }
  }
}

// ---------------- FC GEMM: out[b,t,v] = h1(t) . W_fc[v,:] + b_fc[v] ----------------
// A = h1 history [T*B][H] fp16, B = W_fc [V][H] fp16 (B^T form). 128x128 tile/wg.
__global__ __launch_bounds__(256) void fc_kernel(
    const _Float16* __restrict__ A,    // h1h + BH
    const _Float16* __restrict__ Wfc,  // [V][H] fp16
    const float* __restrict__ bfc,     // [V]
    float* __restrict__ out) {         // [B][T][V]
  __shared__ __align__(16) _Float16 As[128 * 64];
  __shared__ __align__(16) _Float16 Bs[128 * 64];
  const int tid  = threadIdx.x;
  const int wv   = tid >> 6;
  const int lane = tid & 63;
  const int l15  = lane & 15;
  const int q    = lane >> 4;
  const int t    = blockIdx.y;   // M-tile == one timestep (128 b rows)
  const int vt   = blockIdx.x;   // N-tile

  const _Float16* Ag = A   + (size_t)t * BH;
  const _Float16* Bg = Wfc + (size_t)vt * 128 * HDIM;

  floatx4 acc[4][4];
#pragma unroll
  for (int i = 0; i < 4; ++i)
#pragma unroll
    for (int jj = 0; jj < 4; ++jj) { floatx4 zz = {0.f,0.f,0.f,0.f}; acc[i][jj] = zz; }

  const int rowoff = (wv >> 1) * 64;
  const int coloff = (wv & 1) * 64;
  const int wbase  = wv * 1024;   // wave-uniform LDS byte offset

  for (int kk = 0; kk < HDIM; kk += 64) {
    // stage A,B tiles [128 x 64] fp16 with XOR(row&7) chunk swizzle
#pragma unroll
    for (int r = 0; r < 4; ++r) {
      int c   = r * 256 + tid;         // chunk 0..1023; LDS byte off = c*16
      int row = c >> 3;
      int gch = ((c & 7) ^ (row & 7)) << 3;  // swizzled source chunk (halves)
      async16((char*)As + r * 4096 + wbase, Ag + row * HDIM + kk + gch);
      async16((char*)Bs + r * 4096 + wbase, Bg + row * HDIM + kk + gch);
    }
    __syncthreads();
#pragma unroll
    for (int k2 = 0; k2 < 64; k2 += 32) {
      half8 af[4], bf[4];
      const int w = (k2 >> 3) + q;     // wanted chunk index 0..7
#pragma unroll
      for (int i = 0; i < 4; ++i) {
        int rA = rowoff + i * 16 + l15;
        af[i] = *(const half8*)&As[rA * 64 + ((w ^ (rA & 7)) << 3)];
        int rB = coloff + i * 16 + l15;
        bf[i] = *(const half8*)&Bs[rB * 64 + ((w ^ (rB & 7)) << 3)];
      }
#pragma unroll
      for (int i = 0; i < 4; ++i)
#pragma unroll
        for (int jj = 0; jj < 4; ++jj)
          acc[i][jj] = __builtin_amdgcn_mfma_f32_16x16x32_f16(af[i], bf[jj], acc[i][jj], 0, 0, 0);
    }
    __syncthreads();
  }

#pragma unroll
  for (int i = 0; i < 4; ++i) {
    int b0 = rowoff + i * 16 + q * 4;
#pragma unroll
    for (int jj = 0; jj < 4; ++jj) {
      int v = vt * 128 + coloff + jj * 16 + l15;
      float bias = bfc[v];
#pragma unroll
      for (int r = 0; r < 4; ++r) {
        long o = (long)(b0 + r) * (T_STEPS * VDIM) + (long)t * VDIM + v;
        out[o] = acc[i][jj][r] + bias;
      }
    }
  }
}

// ---------------- launch ----------------
extern "C" void kernel_launch(void* const* d_in, const int* in_sizes, int n_in,
                              void* d_out, int out_size, void* d_ws, size_t ws_size,
                              hipStream_t stream) {
  const float* x    = (const float*)d_in[0];
  const float* Wih0 = (const float*)d_in[1];
  const float* Whh0 = (const float*)d_in[2];
  const float* bih0 = (const float*)d_in[3];
  const float* bhh0 = (const float*)d_in[4];
  const float* Wih1 = (const float*)d_in[5];
  const float* Whh1 = (const float*)d_in[6];
  const float* bih1 = (const float*)d_in[7];
  const float* bhh1 = (const float*)d_in[8];
  const float* Wfc  = (const float*)d_in[9];
  const float* bfc  = (const float*)d_in[10];

  // workspace layout (~82.6 MB total, unchanged; first 256 B unused)
  char* w = (char*)d_ws;
  _Float16* h0buf = (_Float16*)(w + 256);                 // 2*BH fp16 = 512 KB
  _Float16* h1h   = (_Float16*)(w + 256 + 2 * BH * 2);    // (T+1)*BH fp16
  size_t off = 256 + (size_t)2 * BH * 2 + (size_t)(T_STEPS + 1) * BH * 2;
  _Float16* W0h16 = (_Float16*)(w + off); off += (size_t)HDIM * HDIM * 2;
  _Float16* W1i16 = (_Float16*)(w + off); off += (size_t)HDIM * HDIM * 2;
  _Float16* W1h16 = (_Float16*)(w + off); off += (size_t)HDIM * HDIM * 2;
  _Float16* Wfc16 = (_Float16*)(w + off); off += (size_t)VDIM * HDIM * 2;

  // sync counters live in the first 64 KB of d_out's [B,T,V] region — this
  // region is fully overwritten by fc_kernel afterwards (stream-ordered).
  unsigned* cnt0 = (unsigned*)d_out;           // [8][256] x 16B stride = 32 KB
  unsigned* cnt1 = cnt0 + 8192;                // another 32 KB
  hipMemsetAsync(d_out, 0, 65536, stream);
  // zero h0buf slot 1 (=h0(-1)) and h1h slot 0 (=h1(-1)) (contiguous)
  hipMemsetAsync((void*)(h0buf + BH), 0, (size_t)2 * BH * 2, stream);

  // weight conversion fp32 -> fp16
  f32_to_f16_kernel<<<(HDIM * HDIM / 4 + 255) / 256, 256, 0, stream>>>(Whh0, W0h16, HDIM * HDIM / 4);
  f32_to_f16_kernel<<<(HDIM * HDIM / 4 + 255) / 256, 256, 0, stream>>>(Wih1, W1i16, HDIM * HDIM / 4);
  f32_to_f16_kernel<<<(HDIM * HDIM / 4 + 255) / 256, 256, 0, stream>>>(Whh1, W1h16, HDIM * HDIM / 4);
  f32_to_f16_kernel<<<(VDIM * HDIM / 4 + 255) / 256, 256, 0, stream>>>(Wfc, Wfc16, VDIM * HDIM / 4);

  float* outh = (float*)d_out + (size_t)BATCH * T_STEPS * VDIM;
  rnn_kernel<<<256, 256, 0, stream>>>(x, Wih0, bih0, bhh0, bih1, bhh1,
                                      W0h16, W1i16, W1h16, h0buf, h1h, outh,
                                      cnt0, cnt1);

  fc_kernel<<<dim3(32, 256), 256, 0, stream>>>(h1h + BH, Wfc16, bfc, (float*)d_out);
}